// Round 1
// baseline (2271.394 us; speedup 1.0000x reference)
//
#include <hip/hip_runtime.h>
#include <math.h>

#define NN 50000
#define NE 800000
#define HD 128
#define NG 500

// ---------------- degree / norm ----------------
__global__ void k_deg_init(float* __restrict__ deg) {
    int i = blockIdx.x * blockDim.x + threadIdx.x;
    if (i < NN) deg[i] = 1.0f;  // self-loop contributes 1
}

__global__ void k_deg_acc(const int* __restrict__ col, float* __restrict__ deg) {
    int e = blockIdx.x * blockDim.x + threadIdx.x;
    if (e < NE) unsafeAtomicAdd(&deg[col[e]], 1.0f);
}

__global__ void k_dinv(float* __restrict__ deg) {
    int i = blockIdx.x * blockDim.x + threadIdx.x;
    if (i < NN) deg[i] = 1.0f / sqrtf(deg[i]);  // deg >= 1 always
}

// ---------------- GEMM: XW = Hin @ W ; Bout = XW*dinv^2 + b ----------------
__global__ __launch_bounds__(256) void k_gemm(const float* __restrict__ Hin,
                                              const float* __restrict__ W,
                                              const float* __restrict__ b,
                                              const float* __restrict__ dinv,
                                              float* __restrict__ XW,
                                              float* __restrict__ Bout) {
    __shared__ float Hs[64][129];   // padded: 2-way max conflict on reads
    __shared__ float Ws[32][132];   // row stride 528B (16B aligned), pad vs write conflicts

    const int tid = threadIdx.x;
    const int base = blockIdx.x * 64;

    // load H tile [64][128]: 2048 float4, 8 per thread
#pragma unroll
    for (int i = 0; i < 8; ++i) {
        int idx = i * 256 + tid;
        int r = idx >> 5;
        int c4 = idx & 31;
        int row = base + r;
        float4 v = make_float4(0.f, 0.f, 0.f, 0.f);
        if (row < NN) v = *(const float4*)(Hin + (size_t)row * HD + c4 * 4);
        Hs[r][c4 * 4 + 0] = v.x;
        Hs[r][c4 * 4 + 1] = v.y;
        Hs[r][c4 * 4 + 2] = v.z;
        Hs[r][c4 * 4 + 3] = v.w;
    }

    const int tr = tid >> 4;       // 0..15 : 4 rows each
    const int tc = tid & 15;       // 0..15 : 8 cols each
    const int r0 = tr * 4;
    const int c0 = tc * 8;

    float acc[4][8];
#pragma unroll
    for (int i = 0; i < 4; ++i)
#pragma unroll
        for (int j = 0; j < 8; ++j) acc[i][j] = 0.f;

    for (int kc = 0; kc < 4; ++kc) {
        __syncthreads();
        // load W chunk [32][128]: 1024 float4, 4 per thread
#pragma unroll
        for (int i = 0; i < 4; ++i) {
            int idx = i * 256 + tid;
            int kr = idx >> 5;
            int c4 = idx & 31;
            float4 v = *(const float4*)(W + (size_t)(kc * 32 + kr) * HD + c4 * 4);
            *(float4*)&Ws[kr][c4 * 4] = v;
        }
        __syncthreads();
#pragma unroll
        for (int kk = 0; kk < 32; ++kk) {
            const int kg = kc * 32 + kk;
            float4 w0 = *(const float4*)&Ws[kk][c0];
            float4 w1 = *(const float4*)&Ws[kk][c0 + 4];
#pragma unroll
            for (int i = 0; i < 4; ++i) {
                float hv = Hs[r0 + i][kg];
                acc[i][0] += hv * w0.x; acc[i][1] += hv * w0.y;
                acc[i][2] += hv * w0.z; acc[i][3] += hv * w0.w;
                acc[i][4] += hv * w1.x; acc[i][5] += hv * w1.y;
                acc[i][6] += hv * w1.z; acc[i][7] += hv * w1.w;
            }
        }
    }

    float bb[8];
#pragma unroll
    for (int j = 0; j < 8; ++j) bb[j] = b[c0 + j];

#pragma unroll
    for (int i = 0; i < 4; ++i) {
        int row = base + r0 + i;
        if (row >= NN) continue;
        float d = dinv[row];
        float d2 = d * d;
        float4 x0 = make_float4(acc[i][0], acc[i][1], acc[i][2], acc[i][3]);
        float4 x1 = make_float4(acc[i][4], acc[i][5], acc[i][6], acc[i][7]);
        *(float4*)(XW + (size_t)row * HD + c0)     = x0;
        *(float4*)(XW + (size_t)row * HD + c0 + 4) = x1;
        float4 y0 = make_float4(acc[i][0] * d2 + bb[0], acc[i][1] * d2 + bb[1],
                                acc[i][2] * d2 + bb[2], acc[i][3] * d2 + bb[3]);
        float4 y1 = make_float4(acc[i][4] * d2 + bb[4], acc[i][5] * d2 + bb[5],
                                acc[i][6] * d2 + bb[6], acc[i][7] * d2 + bb[7]);
        *(float4*)(Bout + (size_t)row * HD + c0)     = y0;
        *(float4*)(Bout + (size_t)row * HD + c0 + 4) = y1;
    }
}

// ---------------- edge scatter: B[col] += XW[row] * dinv[row]*dinv[col] ----------------
__global__ __launch_bounds__(256) void k_scatter(const float* __restrict__ XW,
                                                 float* __restrict__ B,
                                                 const int* __restrict__ row,
                                                 const int* __restrict__ col,
                                                 const float* __restrict__ dinv) {
    int wid = (int)((blockIdx.x * (size_t)blockDim.x + threadIdx.x) >> 6);  // wave id = edge id
    int lane = threadIdx.x & 63;
    if (wid >= NE) return;
    int r = row[wid];
    int c = col[wid];
    float s = dinv[r] * dinv[c];
    float2 v = ((const float2*)(XW + (size_t)r * HD))[lane];
    float* dst = B + (size_t)c * HD + lane * 2;
    unsafeAtomicAdd(dst,     v.x * s);
    unsafeAtomicAdd(dst + 1, v.y * s);
}

// ---------------- ELU in place ----------------
__global__ void k_elu(float* __restrict__ B) {
    int i = blockIdx.x * blockDim.x + threadIdx.x;
    const int n = NN * HD / 2;
    if (i < n) {
        float2 v = ((float2*)B)[i];
        v.x = v.x > 0.f ? v.x : expm1f(v.x);
        v.y = v.y > 0.f ? v.y : expm1f(v.y);
        ((float2*)B)[i] = v;
    }
}

// ---------------- pool: per-node dot with Wout, segment sum over graphs ----------------
__global__ __launch_bounds__(256) void k_pool(const float* __restrict__ B,
                                              const float* __restrict__ Wout,
                                              const int* __restrict__ batch,
                                              float* __restrict__ gsum,
                                              float* __restrict__ gcnt) {
    int wid = (int)((blockIdx.x * (size_t)blockDim.x + threadIdx.x) >> 6);  // node id
    int lane = threadIdx.x & 63;
    if (wid >= NN) return;
    float2 h = ((const float2*)(B + (size_t)wid * HD))[lane];
    float2 w = ((const float2*)Wout)[lane];
    float v = h.x * w.x + h.y * w.y;
#pragma unroll
    for (int off = 32; off > 0; off >>= 1) v += __shfl_down(v, off);
    if (lane == 0) {
        int g = batch[wid];
        unsafeAtomicAdd(&gsum[g], v);
        unsafeAtomicAdd(&gcnt[g], 1.0f);
    }
}

__global__ void k_final(const float* __restrict__ gsum,
                        const float* __restrict__ gcnt,
                        const float* __restrict__ bout,
                        float* __restrict__ out) {
    int g = blockIdx.x * blockDim.x + threadIdx.x;
    if (g < NG) out[g] = gsum[g] / fmaxf(gcnt[g], 1.0f) + bout[0];
}

extern "C" void kernel_launch(void* const* d_in, const int* in_sizes, int n_in,
                              void* d_out, int out_size, void* d_ws, size_t ws_size,
                              hipStream_t stream) {
    const float* x    = (const float*)d_in[0];
    const float* W0   = (const float*)d_in[1];
    const float* b0   = (const float*)d_in[2];
    const float* W1   = (const float*)d_in[3];
    const float* b1   = (const float*)d_in[4];
    const float* W2   = (const float*)d_in[5];
    const float* b2   = (const float*)d_in[6];
    const float* Wout = (const float*)d_in[7];
    const float* bout = (const float*)d_in[8];
    const int*   erow = (const int*)d_in[9];
    const int*   ecol = erow + NE;
    const int*   batch = (const int*)d_in[10];
    float* out = (float*)d_out;

    float* A    = (float*)d_ws;                 // xw buffer [NN][HD]
    float* B    = A + (size_t)NN * HD;          // h buffer  [NN][HD]
    float* dinv = B + (size_t)NN * HD;          // deg -> dinv [NN]
    float* gsum = dinv + NN;                    // [NG]
    // gcnt = gsum + NG

    k_deg_init<<<(NN + 255) / 256, 256, 0, stream>>>(dinv);
    k_deg_acc<<<(NE + 255) / 256, 256, 0, stream>>>(ecol, dinv);
    k_dinv<<<(NN + 255) / 256, 256, 0, stream>>>(dinv);
    hipMemsetAsync(gsum, 0, 2 * NG * sizeof(float), stream);

    const float* Hin = x;
    const float* Wl[3] = {W0, W1, W2};
    const float* bl[3] = {b0, b1, b2};
    for (int l = 0; l < 3; ++l) {
        k_gemm<<<(NN + 63) / 64, 256, 0, stream>>>(Hin, Wl[l], bl[l], dinv, A, B);
        k_scatter<<<NE / 4, 256, 0, stream>>>(A, B, erow, ecol, dinv);
        k_elu<<<(NN * HD / 2 + 255) / 256, 256, 0, stream>>>(B);
        Hin = B;
    }
    k_pool<<<(NN + 3) / 4, 256, 0, stream>>>(B, Wout, batch, gsum, gsum + NG);
    k_final<<<(NG + 255) / 256, 256, 0, stream>>>(gsum, gsum + NG, bout, out);
}

// Round 2
// 582.786 us; speedup vs baseline: 3.8975x; 3.8975x over previous
//
#include <hip/hip_runtime.h>
#include <math.h>

#define NN 50000
#define NE 800000
#define HD 128
#define NG 500

// ---------------- CSR build: count, scan, fill ----------------
__global__ void k_count(const int* __restrict__ col, int* __restrict__ cnt) {
    int e = blockIdx.x * blockDim.x + threadIdx.x;
    if (e < NE) atomicAdd(&cnt[col[e]], 1);
}

__global__ void k_dinv(const int* __restrict__ cnt, float* __restrict__ dinv) {
    int i = blockIdx.x * blockDim.x + threadIdx.x;
    if (i < NN) dinv[i] = rsqrtf((float)(cnt[i] + 1));  // +1 self-loop
}

// single-block chunked exclusive scan of cnt[NN] -> rowptr[NN+1]
__global__ __launch_bounds__(1024) void k_scan(const int* __restrict__ cnt,
                                               int* __restrict__ rowptr) {
    __shared__ int wsum[16];
    __shared__ int woff[16];
    __shared__ int stotal;
    const int tid = threadIdx.x;
    const int lane = tid & 63;
    const int wv = tid >> 6;
    int carry = 0;
    const int CH = (NN + 1023) / 1024;
    for (int ch = 0; ch < CH; ++ch) {
        int idx = ch * 1024 + tid;
        int v = (idx < NN) ? cnt[idx] : 0;
        int incl = v;
#pragma unroll
        for (int off = 1; off < 64; off <<= 1) {
            int t = __shfl_up(incl, off);
            if (lane >= off) incl += t;
        }
        if (lane == 63) wsum[wv] = incl;
        __syncthreads();
        if (wv == 0) {
            int s = (lane < 16) ? wsum[lane] : 0;
            int inc2 = s;
#pragma unroll
            for (int off = 1; off < 16; off <<= 1) {
                int t = __shfl_up(inc2, off);
                if (lane >= off) inc2 += t;
            }
            if (lane < 16) woff[lane] = inc2 - s;
            if (lane == 15) stotal = inc2;
        }
        __syncthreads();
        if (idx < NN) rowptr[idx] = carry + woff[wv] + (incl - v);
        carry += stotal;
        __syncthreads();
    }
    if (tid == 0) rowptr[NN] = carry;
}

__global__ void k_cursor(const int* __restrict__ rowptr, int* __restrict__ cursor) {
    int i = blockIdx.x * blockDim.x + threadIdx.x;
    if (i < NN) cursor[i] = rowptr[i];
}

// rec[p] = {src, dinv[src]} bucketed by destination
__global__ void k_fill(const int* __restrict__ row, const int* __restrict__ col,
                       const float* __restrict__ dinv, int* __restrict__ cursor,
                       int2* __restrict__ rec) {
    int e = blockIdx.x * blockDim.x + threadIdx.x;
    if (e < NE) {
        int r = row[e];
        int c = col[e];
        int p = atomicAdd(&cursor[c], 1);
        rec[p] = make_int2(r, __float_as_int(dinv[r]));
    }
}

// ---------------- GEMM: XW = Hin @ W ; Bout = XW*dinv^2 + b (self-loop term) ----------------
__global__ __launch_bounds__(256) void k_gemm(const float* __restrict__ Hin,
                                              const float* __restrict__ W,
                                              const float* __restrict__ b,
                                              const float* __restrict__ dinv,
                                              float* __restrict__ XW,
                                              float* __restrict__ Bout) {
    __shared__ float Hs[64][129];
    __shared__ float Ws[32][132];

    const int tid = threadIdx.x;
    const int base = blockIdx.x * 64;

#pragma unroll
    for (int i = 0; i < 8; ++i) {
        int idx = i * 256 + tid;
        int r = idx >> 5;
        int c4 = idx & 31;
        int row = base + r;
        float4 v = make_float4(0.f, 0.f, 0.f, 0.f);
        if (row < NN) v = *(const float4*)(Hin + (size_t)row * HD + c4 * 4);
        Hs[r][c4 * 4 + 0] = v.x;
        Hs[r][c4 * 4 + 1] = v.y;
        Hs[r][c4 * 4 + 2] = v.z;
        Hs[r][c4 * 4 + 3] = v.w;
    }

    const int tr = tid >> 4;
    const int tc = tid & 15;
    const int r0 = tr * 4;
    const int c0 = tc * 8;

    float acc[4][8];
#pragma unroll
    for (int i = 0; i < 4; ++i)
#pragma unroll
        for (int j = 0; j < 8; ++j) acc[i][j] = 0.f;

    for (int kc = 0; kc < 4; ++kc) {
        __syncthreads();
#pragma unroll
        for (int i = 0; i < 4; ++i) {
            int idx = i * 256 + tid;
            int kr = idx >> 5;
            int c4 = idx & 31;
            float4 v = *(const float4*)(W + (size_t)(kc * 32 + kr) * HD + c4 * 4);
            *(float4*)&Ws[kr][c4 * 4] = v;
        }
        __syncthreads();
#pragma unroll
        for (int kk = 0; kk < 32; ++kk) {
            const int kg = kc * 32 + kk;
            float4 w0 = *(const float4*)&Ws[kk][c0];
            float4 w1 = *(const float4*)&Ws[kk][c0 + 4];
#pragma unroll
            for (int i = 0; i < 4; ++i) {
                float hv = Hs[r0 + i][kg];
                acc[i][0] += hv * w0.x; acc[i][1] += hv * w0.y;
                acc[i][2] += hv * w0.z; acc[i][3] += hv * w0.w;
                acc[i][4] += hv * w1.x; acc[i][5] += hv * w1.y;
                acc[i][6] += hv * w1.z; acc[i][7] += hv * w1.w;
            }
        }
    }

    float bb[8];
#pragma unroll
    for (int j = 0; j < 8; ++j) bb[j] = b[c0 + j];

#pragma unroll
    for (int i = 0; i < 4; ++i) {
        int row = base + r0 + i;
        if (row >= NN) continue;
        float d = dinv[row];
        float d2 = d * d;
        float4 x0 = make_float4(acc[i][0], acc[i][1], acc[i][2], acc[i][3]);
        float4 x1 = make_float4(acc[i][4], acc[i][5], acc[i][6], acc[i][7]);
        *(float4*)(XW + (size_t)row * HD + c0)     = x0;
        *(float4*)(XW + (size_t)row * HD + c0 + 4) = x1;
        float4 y0 = make_float4(acc[i][0] * d2 + bb[0], acc[i][1] * d2 + bb[1],
                                acc[i][2] * d2 + bb[2], acc[i][3] * d2 + bb[3]);
        float4 y1 = make_float4(acc[i][4] * d2 + bb[4], acc[i][5] * d2 + bb[5],
                                acc[i][6] * d2 + bb[6], acc[i][7] * d2 + bb[7]);
        *(float4*)(Bout + (size_t)row * HD + c0)     = y0;
        *(float4*)(Bout + (size_t)row * HD + c0 + 4) = y1;
    }
}

// ---------------- gather: B[i] = elu(B[i] + dinv[i] * sum_{e in CSR[i]} XW[src_e]*dinv[src_e]) ----------------
__global__ __launch_bounds__(256) void k_gather(const float* __restrict__ XW,
                                                float* __restrict__ B,
                                                const int2* __restrict__ rec,
                                                const int* __restrict__ rowptr,
                                                const float* __restrict__ dinv) {
    int node = blockIdx.x * 4 + (threadIdx.x >> 6);
    int lane = threadIdx.x & 63;
    if (node >= NN) return;
    int s = rowptr[node];
    int e = rowptr[node + 1];
    float2 acc = make_float2(0.f, 0.f);
    int j = s;
    for (; j + 1 < e; j += 2) {
        int2 r0 = rec[j];
        int2 r1 = rec[j + 1];
        float2 v0 = ((const float2*)(XW + (size_t)r0.x * HD))[lane];
        float2 v1 = ((const float2*)(XW + (size_t)r1.x * HD))[lane];
        float s0 = __int_as_float(r0.y);
        float s1 = __int_as_float(r1.y);
        acc.x += v0.x * s0 + v1.x * s1;
        acc.y += v0.y * s0 + v1.y * s1;
    }
    if (j < e) {
        int2 r0 = rec[j];
        float2 v0 = ((const float2*)(XW + (size_t)r0.x * HD))[lane];
        float s0 = __int_as_float(r0.y);
        acc.x += v0.x * s0;
        acc.y += v0.y * s0;
    }
    float di = dinv[node];
    float2 h = ((const float2*)(B + (size_t)node * HD))[lane];
    h.x += di * acc.x;
    h.y += di * acc.y;
    h.x = h.x > 0.f ? h.x : expm1f(h.x);
    h.y = h.y > 0.f ? h.y : expm1f(h.y);
    ((float2*)(B + (size_t)node * HD))[lane] = h;
}

// ---------------- pool ----------------
__global__ __launch_bounds__(256) void k_pool(const float* __restrict__ B,
                                              const float* __restrict__ Wout,
                                              const int* __restrict__ batch,
                                              float* __restrict__ gsum,
                                              float* __restrict__ gcnt) {
    int wid = (int)((blockIdx.x * (size_t)blockDim.x + threadIdx.x) >> 6);
    int lane = threadIdx.x & 63;
    if (wid >= NN) return;
    float2 h = ((const float2*)(B + (size_t)wid * HD))[lane];
    float2 w = ((const float2*)Wout)[lane];
    float v = h.x * w.x + h.y * w.y;
#pragma unroll
    for (int off = 32; off > 0; off >>= 1) v += __shfl_down(v, off);
    if (lane == 0) {
        int g = batch[wid];
        unsafeAtomicAdd(&gsum[g], v);
        unsafeAtomicAdd(&gcnt[g], 1.0f);
    }
}

__global__ void k_final(const float* __restrict__ gsum,
                        const float* __restrict__ gcnt,
                        const float* __restrict__ bout,
                        float* __restrict__ out) {
    int g = blockIdx.x * blockDim.x + threadIdx.x;
    if (g < NG) out[g] = gsum[g] / fmaxf(gcnt[g], 1.0f) + bout[0];
}

extern "C" void kernel_launch(void* const* d_in, const int* in_sizes, int n_in,
                              void* d_out, int out_size, void* d_ws, size_t ws_size,
                              hipStream_t stream) {
    const float* x    = (const float*)d_in[0];
    const float* W0   = (const float*)d_in[1];
    const float* b0   = (const float*)d_in[2];
    const float* W1   = (const float*)d_in[3];
    const float* b1   = (const float*)d_in[4];
    const float* W2   = (const float*)d_in[5];
    const float* b2   = (const float*)d_in[6];
    const float* Wout = (const float*)d_in[7];
    const float* bout = (const float*)d_in[8];
    const int*   erow = (const int*)d_in[9];
    const int*   ecol = erow + NE;
    const int*   batch = (const int*)d_in[10];
    float* out = (float*)d_out;

    float* A      = (float*)d_ws;                  // XW buffer [NN][HD]
    float* B      = A + (size_t)NN * HD;           // h buffer  [NN][HD]
    float* dinv   = B + (size_t)NN * HD;           // [NN]
    float* gsum   = dinv + NN;                     // [NG]
    float* gcnt   = gsum + NG;                     // [NG]
    int*   cnt    = (int*)(gcnt + NG);             // [NN] (reused as cursor)
    int*   rowptr = cnt + NN;                      // [NN+1]
    int2*  rec    = (int2*)(rowptr + NN + 1);      // [NE]

    hipMemsetAsync(cnt, 0, NN * sizeof(int), stream);
    hipMemsetAsync(gsum, 0, 2 * NG * sizeof(float), stream);
    k_count<<<(NE + 255) / 256, 256, 0, stream>>>(ecol, cnt);
    k_dinv<<<(NN + 255) / 256, 256, 0, stream>>>(cnt, dinv);
    k_scan<<<1, 1024, 0, stream>>>(cnt, rowptr);
    k_cursor<<<(NN + 255) / 256, 256, 0, stream>>>(rowptr, cnt);
    k_fill<<<(NE + 255) / 256, 256, 0, stream>>>(erow, ecol, dinv, cnt, rec);

    const float* Hin = x;
    const float* Wl[3] = {W0, W1, W2};
    const float* bl[3] = {b0, b1, b2};
    for (int l = 0; l < 3; ++l) {
        k_gemm<<<(NN + 63) / 64, 256, 0, stream>>>(Hin, Wl[l], bl[l], dinv, A, B);
        k_gather<<<(NN + 3) / 4, 256, 0, stream>>>(A, B, rec, rowptr, dinv);
        Hin = B;
    }
    k_pool<<<(NN + 3) / 4, 256, 0, stream>>>(B, Wout, batch, gsum, gcnt);
    k_final<<<(NG + 255) / 256, 256, 0, stream>>>(gsum, gcnt, bout, out);
}

// Round 3
// 467.848 us; speedup vs baseline: 4.8550x; 1.2457x over previous
//
#include <hip/hip_runtime.h>
#include <math.h>

#define NN 50000
#define NE 800000
#define HD 128
#define NG 500

// ---------------- CSR build: count, scan, fill ----------------
__global__ void k_count(const int* __restrict__ col, int* __restrict__ cnt) {
    int e = blockIdx.x * blockDim.x + threadIdx.x;
    if (e < NE) atomicAdd(&cnt[col[e]], 1);
}

__global__ void k_dinv(const int* __restrict__ cnt, float* __restrict__ dinv) {
    int i = blockIdx.x * blockDim.x + threadIdx.x;
    if (i < NN) dinv[i] = rsqrtf((float)(cnt[i] + 1));  // +1 self-loop
}

// single-block chunked exclusive scan of cnt[NN] -> rowptr[NN+1]
__global__ __launch_bounds__(1024) void k_scan(const int* __restrict__ cnt,
                                               int* __restrict__ rowptr) {
    __shared__ int wsum[16];
    __shared__ int woff[16];
    __shared__ int stotal;
    const int tid = threadIdx.x;
    const int lane = tid & 63;
    const int wv = tid >> 6;
    int carry = 0;
    const int CH = (NN + 1023) / 1024;
    for (int ch = 0; ch < CH; ++ch) {
        int idx = ch * 1024 + tid;
        int v = (idx < NN) ? cnt[idx] : 0;
        int incl = v;
#pragma unroll
        for (int off = 1; off < 64; off <<= 1) {
            int t = __shfl_up(incl, off);
            if (lane >= off) incl += t;
        }
        if (lane == 63) wsum[wv] = incl;
        __syncthreads();
        if (wv == 0) {
            int s = (lane < 16) ? wsum[lane] : 0;
            int inc2 = s;
#pragma unroll
            for (int off = 1; off < 16; off <<= 1) {
                int t = __shfl_up(inc2, off);
                if (lane >= off) inc2 += t;
            }
            if (lane < 16) woff[lane] = inc2 - s;
            if (lane == 15) stotal = inc2;
        }
        __syncthreads();
        if (idx < NN) rowptr[idx] = carry + woff[wv] + (incl - v);
        carry += stotal;
        __syncthreads();
    }
    if (tid == 0) rowptr[NN] = carry;
}

__global__ void k_cursor(const int* __restrict__ rowptr, int* __restrict__ cursor) {
    int i = blockIdx.x * blockDim.x + threadIdx.x;
    if (i < NN) cursor[i] = rowptr[i];
}

// rec[p] = {src, dinv[src]} bucketed by destination
__global__ void k_fill(const int* __restrict__ row, const int* __restrict__ col,
                       const float* __restrict__ dinv, int* __restrict__ cursor,
                       int2* __restrict__ rec) {
    int e = blockIdx.x * blockDim.x + threadIdx.x;
    if (e < NE) {
        int r = row[e];
        int c = col[e];
        int p = atomicAdd(&cursor[c], 1);
        rec[p] = make_int2(r, __float_as_int(dinv[r]));
    }
}

// gptr[g] = first node index with batch[node] >= g  (batch is sorted)
__global__ void k_gptr(const int* __restrict__ batch, int* __restrict__ gptr) {
    int g = blockIdx.x * blockDim.x + threadIdx.x;
    if (g > NG) return;
    int lo = 0, hi = NN;
    while (lo < hi) {
        int mid = (lo + hi) >> 1;
        if (batch[mid] < g) lo = mid + 1; else hi = mid;
    }
    gptr[g] = lo;
}

// ---------------- GEMM: XW = Hin @ W ; Bout = XW*dinv^2 + b (self-loop term) ----------------
__global__ __launch_bounds__(256) void k_gemm(const float* __restrict__ Hin,
                                              const float* __restrict__ W,
                                              const float* __restrict__ b,
                                              const float* __restrict__ dinv,
                                              float* __restrict__ XW,
                                              float* __restrict__ Bout) {
    __shared__ float Hs[64][129];
    __shared__ float Ws[32][132];

    const int tid = threadIdx.x;
    const int base = blockIdx.x * 64;

#pragma unroll
    for (int i = 0; i < 8; ++i) {
        int idx = i * 256 + tid;
        int r = idx >> 5;
        int c4 = idx & 31;
        int row = base + r;
        float4 v = make_float4(0.f, 0.f, 0.f, 0.f);
        if (row < NN) v = *(const float4*)(Hin + (size_t)row * HD + c4 * 4);
        Hs[r][c4 * 4 + 0] = v.x;
        Hs[r][c4 * 4 + 1] = v.y;
        Hs[r][c4 * 4 + 2] = v.z;
        Hs[r][c4 * 4 + 3] = v.w;
    }

    const int tr = tid >> 4;
    const int tc = tid & 15;
    const int r0 = tr * 4;
    const int c0 = tc * 8;

    float acc[4][8];
#pragma unroll
    for (int i = 0; i < 4; ++i)
#pragma unroll
        for (int j = 0; j < 8; ++j) acc[i][j] = 0.f;

    for (int kc = 0; kc < 4; ++kc) {
        __syncthreads();
#pragma unroll
        for (int i = 0; i < 4; ++i) {
            int idx = i * 256 + tid;
            int kr = idx >> 5;
            int c4 = idx & 31;
            float4 v = *(const float4*)(W + (size_t)(kc * 32 + kr) * HD + c4 * 4);
            *(float4*)&Ws[kr][c4 * 4] = v;
        }
        __syncthreads();
#pragma unroll
        for (int kk = 0; kk < 32; ++kk) {
            const int kg = kc * 32 + kk;
            float4 w0 = *(const float4*)&Ws[kk][c0];
            float4 w1 = *(const float4*)&Ws[kk][c0 + 4];
#pragma unroll
            for (int i = 0; i < 4; ++i) {
                float hv = Hs[r0 + i][kg];
                acc[i][0] += hv * w0.x; acc[i][1] += hv * w0.y;
                acc[i][2] += hv * w0.z; acc[i][3] += hv * w0.w;
                acc[i][4] += hv * w1.x; acc[i][5] += hv * w1.y;
                acc[i][6] += hv * w1.z; acc[i][7] += hv * w1.w;
            }
        }
    }

    float bb[8];
#pragma unroll
    for (int j = 0; j < 8; ++j) bb[j] = b[c0 + j];

#pragma unroll
    for (int i = 0; i < 4; ++i) {
        int row = base + r0 + i;
        if (row >= NN) continue;
        float d = dinv[row];
        float d2 = d * d;
        float4 x0 = make_float4(acc[i][0], acc[i][1], acc[i][2], acc[i][3]);
        float4 x1 = make_float4(acc[i][4], acc[i][5], acc[i][6], acc[i][7]);
        *(float4*)(XW + (size_t)row * HD + c0)     = x0;
        *(float4*)(XW + (size_t)row * HD + c0 + 4) = x1;
        float4 y0 = make_float4(acc[i][0] * d2 + bb[0], acc[i][1] * d2 + bb[1],
                                acc[i][2] * d2 + bb[2], acc[i][3] * d2 + bb[3]);
        float4 y1 = make_float4(acc[i][4] * d2 + bb[4], acc[i][5] * d2 + bb[5],
                                acc[i][6] * d2 + bb[6], acc[i][7] * d2 + bb[7]);
        *(float4*)(Bout + (size_t)row * HD + c0)     = y0;
        *(float4*)(Bout + (size_t)row * HD + c0 + 4) = y1;
    }
}

// ---------------- gather: B[i] = elu(B[i] + dinv[i] * sum_{e in CSR[i]} XW[src_e]*dinv[src_e]) ----------------
__global__ __launch_bounds__(256) void k_gather(const float* __restrict__ XW,
                                                float* __restrict__ B,
                                                const int2* __restrict__ rec,
                                                const int* __restrict__ rowptr,
                                                const float* __restrict__ dinv) {
    int node = blockIdx.x * 4 + (threadIdx.x >> 6);
    int lane = threadIdx.x & 63;
    if (node >= NN) return;
    int s = rowptr[node];
    int e = rowptr[node + 1];
    float2 acc = make_float2(0.f, 0.f);
    int j = s;
    for (; j + 1 < e; j += 2) {
        int2 r0 = rec[j];
        int2 r1 = rec[j + 1];
        float2 v0 = ((const float2*)(XW + (size_t)r0.x * HD))[lane];
        float2 v1 = ((const float2*)(XW + (size_t)r1.x * HD))[lane];
        float s0 = __int_as_float(r0.y);
        float s1 = __int_as_float(r1.y);
        acc.x += v0.x * s0 + v1.x * s1;
        acc.y += v0.y * s0 + v1.y * s1;
    }
    if (j < e) {
        int2 r0 = rec[j];
        float2 v0 = ((const float2*)(XW + (size_t)r0.x * HD))[lane];
        float s0 = __int_as_float(r0.y);
        acc.x += v0.x * s0;
        acc.y += v0.y * s0;
    }
    float di = dinv[node];
    float2 h = ((const float2*)(B + (size_t)node * HD))[lane];
    h.x += di * acc.x;
    h.y += di * acc.y;
    h.x = h.x > 0.f ? h.x : expm1f(h.x);
    h.y = h.y > 0.f ? h.y : expm1f(h.y);
    ((float2*)(B + (size_t)node * HD))[lane] = h;
}

// ---------------- pool: one block per graph, no atomics ----------------
__global__ __launch_bounds__(256) void k_pool(const float* __restrict__ B,
                                              const float* __restrict__ Wout,
                                              const float* __restrict__ bout,
                                              const int* __restrict__ gptr,
                                              float* __restrict__ out) {
    __shared__ float wpart[4];
    const int g = blockIdx.x;
    const int lane = threadIdx.x & 63;
    const int wv = threadIdx.x >> 6;
    const int s = gptr[g];
    const int e = gptr[g + 1];

    float2 w = ((const float2*)Wout)[lane];
    float acc = 0.f;
    for (int node = s + wv; node < e; node += 4) {
        float2 h = ((const float2*)(B + (size_t)node * HD))[lane];
        acc += h.x * w.x + h.y * w.y;
    }
#pragma unroll
    for (int off = 32; off > 0; off >>= 1) acc += __shfl_down(acc, off);
    if (lane == 0) wpart[wv] = acc;
    __syncthreads();
    if (threadIdx.x == 0) {
        float total = wpart[0] + wpart[1] + wpart[2] + wpart[3];
        int cnt = e - s;
        out[g] = total / (float)(cnt > 0 ? cnt : 1) + bout[0];
    }
}

extern "C" void kernel_launch(void* const* d_in, const int* in_sizes, int n_in,
                              void* d_out, int out_size, void* d_ws, size_t ws_size,
                              hipStream_t stream) {
    const float* x    = (const float*)d_in[0];
    const float* W0   = (const float*)d_in[1];
    const float* b0   = (const float*)d_in[2];
    const float* W1   = (const float*)d_in[3];
    const float* b1   = (const float*)d_in[4];
    const float* W2   = (const float*)d_in[5];
    const float* b2   = (const float*)d_in[6];
    const float* Wout = (const float*)d_in[7];
    const float* bout = (const float*)d_in[8];
    const int*   erow = (const int*)d_in[9];
    const int*   ecol = erow + NE;
    const int*   batch = (const int*)d_in[10];
    float* out = (float*)d_out;

    float* A      = (float*)d_ws;                  // XW buffer [NN][HD]
    float* B      = A + (size_t)NN * HD;           // h buffer  [NN][HD]
    float* dinv   = B + (size_t)NN * HD;           // [NN]
    int*   cnt    = (int*)(dinv + NN);             // [NN] (reused as cursor)
    int*   rowptr = cnt + NN;                      // [NN+1]
    int*   gptr   = rowptr + NN + 1;               // [NG+1]
    int2*  rec    = (int2*)(gptr + NG + 1);        // [NE]

    hipMemsetAsync(cnt, 0, NN * sizeof(int), stream);
    k_count<<<(NE + 255) / 256, 256, 0, stream>>>(ecol, cnt);
    k_dinv<<<(NN + 255) / 256, 256, 0, stream>>>(cnt, dinv);
    k_scan<<<1, 1024, 0, stream>>>(cnt, rowptr);
    k_cursor<<<(NN + 255) / 256, 256, 0, stream>>>(rowptr, cnt);
    k_fill<<<(NE + 255) / 256, 256, 0, stream>>>(erow, ecol, dinv, cnt, rec);
    k_gptr<<<(NG + 1 + 255) / 256, 256, 0, stream>>>(batch, gptr);

    const float* Hin = x;
    const float* Wl[3] = {W0, W1, W2};
    const float* bl[3] = {b0, b1, b2};
    for (int l = 0; l < 3; ++l) {
        k_gemm<<<(NN + 63) / 64, 256, 0, stream>>>(Hin, Wl[l], bl[l], dinv, A, B);
        k_gather<<<(NN + 3) / 4, 256, 0, stream>>>(A, B, rec, rowptr, dinv);
        Hin = B;
    }
    k_pool<<<NG, 256, 0, stream>>>(B, Wout, bout, gptr, out);
}

// Round 4
// 456.833 us; speedup vs baseline: 4.9720x; 1.0241x over previous
//
#include <hip/hip_runtime.h>
#include <math.h>

#define NN 50000
#define NE 800000
#define HD 128
#define NG 500

// ---------------- CSR build: count, scan, fill ----------------
__global__ void k_count(const int* __restrict__ col, int* __restrict__ cnt) {
    int e = blockIdx.x * blockDim.x + threadIdx.x;
    if (e < NE) atomicAdd(&cnt[col[e]], 1);
}

__global__ void k_dinv(const int* __restrict__ cnt, float* __restrict__ dinv) {
    int i = blockIdx.x * blockDim.x + threadIdx.x;
    if (i < NN) dinv[i] = rsqrtf((float)(cnt[i] + 1));  // +1 self-loop
}

// single-block chunked exclusive scan of cnt[NN] -> rowptr[NN+1]
__global__ __launch_bounds__(1024) void k_scan(const int* __restrict__ cnt,
                                               int* __restrict__ rowptr) {
    __shared__ int wsum[16];
    __shared__ int woff[16];
    __shared__ int stotal;
    const int tid = threadIdx.x;
    const int lane = tid & 63;
    const int wv = tid >> 6;
    int carry = 0;
    const int CH = (NN + 1023) / 1024;
    for (int ch = 0; ch < CH; ++ch) {
        int idx = ch * 1024 + tid;
        int v = (idx < NN) ? cnt[idx] : 0;
        int incl = v;
#pragma unroll
        for (int off = 1; off < 64; off <<= 1) {
            int t = __shfl_up(incl, off);
            if (lane >= off) incl += t;
        }
        if (lane == 63) wsum[wv] = incl;
        __syncthreads();
        if (wv == 0) {
            int s = (lane < 16) ? wsum[lane] : 0;
            int inc2 = s;
#pragma unroll
            for (int off = 1; off < 16; off <<= 1) {
                int t = __shfl_up(inc2, off);
                if (lane >= off) inc2 += t;
            }
            if (lane < 16) woff[lane] = inc2 - s;
            if (lane == 15) stotal = inc2;
        }
        __syncthreads();
        if (idx < NN) rowptr[idx] = carry + woff[wv] + (incl - v);
        carry += stotal;
        __syncthreads();
    }
    if (tid == 0) rowptr[NN] = carry;
}

__global__ void k_cursor(const int* __restrict__ rowptr, int* __restrict__ cursor) {
    int i = blockIdx.x * blockDim.x + threadIdx.x;
    if (i < NN) cursor[i] = rowptr[i];
}

// rec[p] = {src, dinv[src]} bucketed by destination
__global__ void k_fill(const int* __restrict__ row, const int* __restrict__ col,
                       const float* __restrict__ dinv, int* __restrict__ cursor,
                       int2* __restrict__ rec) {
    int e = blockIdx.x * blockDim.x + threadIdx.x;
    if (e < NE) {
        int r = row[e];
        int c = col[e];
        int p = atomicAdd(&cursor[c], 1);
        rec[p] = make_int2(r, __float_as_int(dinv[r]));
    }
}

// gptr[g] = first node index with batch[node] >= g  (batch is sorted)
__global__ void k_gptr(const int* __restrict__ batch, int* __restrict__ gptr) {
    int g = blockIdx.x * blockDim.x + threadIdx.x;
    if (g > NG) return;
    int lo = 0, hi = NN;
    while (lo < hi) {
        int mid = (lo + hi) >> 1;
        if (batch[mid] < g) lo = mid + 1; else hi = mid;
    }
    gptr[g] = lo;
}

// ---------------- GEMM: XW = Hin @ W ----------------
__global__ __launch_bounds__(256) void k_gemm(const float* __restrict__ Hin,
                                              const float* __restrict__ W,
                                              float* __restrict__ XW) {
    __shared__ float Hs[64][129];
    __shared__ float Ws[32][132];

    const int tid = threadIdx.x;
    const int base = blockIdx.x * 64;

#pragma unroll
    for (int i = 0; i < 8; ++i) {
        int idx = i * 256 + tid;
        int r = idx >> 5;
        int c4 = idx & 31;
        int row = base + r;
        float4 v = make_float4(0.f, 0.f, 0.f, 0.f);
        if (row < NN) v = *(const float4*)(Hin + (size_t)row * HD + c4 * 4);
        Hs[r][c4 * 4 + 0] = v.x;
        Hs[r][c4 * 4 + 1] = v.y;
        Hs[r][c4 * 4 + 2] = v.z;
        Hs[r][c4 * 4 + 3] = v.w;
    }

    const int tr = tid >> 4;
    const int tc = tid & 15;
    const int r0 = tr * 4;
    const int c0 = tc * 8;

    float acc[4][8];
#pragma unroll
    for (int i = 0; i < 4; ++i)
#pragma unroll
        for (int j = 0; j < 8; ++j) acc[i][j] = 0.f;

    for (int kc = 0; kc < 4; ++kc) {
        __syncthreads();
#pragma unroll
        for (int i = 0; i < 4; ++i) {
            int idx = i * 256 + tid;
            int kr = idx >> 5;
            int c4 = idx & 31;
            float4 v = *(const float4*)(W + (size_t)(kc * 32 + kr) * HD + c4 * 4);
            *(float4*)&Ws[kr][c4 * 4] = v;
        }
        __syncthreads();
#pragma unroll
        for (int kk = 0; kk < 32; ++kk) {
            const int kg = kc * 32 + kk;
            float4 w0 = *(const float4*)&Ws[kk][c0];
            float4 w1 = *(const float4*)&Ws[kk][c0 + 4];
#pragma unroll
            for (int i = 0; i < 4; ++i) {
                float hv = Hs[r0 + i][kg];
                acc[i][0] += hv * w0.x; acc[i][1] += hv * w0.y;
                acc[i][2] += hv * w0.z; acc[i][3] += hv * w0.w;
                acc[i][4] += hv * w1.x; acc[i][5] += hv * w1.y;
                acc[i][6] += hv * w1.z; acc[i][7] += hv * w1.w;
            }
        }
    }

#pragma unroll
    for (int i = 0; i < 4; ++i) {
        int row = base + r0 + i;
        if (row >= NN) continue;
        float4 x0 = make_float4(acc[i][0], acc[i][1], acc[i][2], acc[i][3]);
        float4 x1 = make_float4(acc[i][4], acc[i][5], acc[i][6], acc[i][7]);
        *(float4*)(XW + (size_t)row * HD + c0)     = x0;
        *(float4*)(XW + (size_t)row * HD + c0 + 4) = x1;
    }
}

// ---------------- gather + self-loop + bias + ELU ----------------
// B[i] = elu( dinv[i]*(dinv[i]*XW[i] + sum_{e in CSR[i]} XW[src_e]*dinv[src_e]) + b )
__global__ __launch_bounds__(256) void k_gather(const float* __restrict__ XW,
                                                float* __restrict__ B,
                                                const int2* __restrict__ rec,
                                                const int* __restrict__ rowptr,
                                                const float* __restrict__ dinv,
                                                const float* __restrict__ bias) {
    int node = blockIdx.x * 4 + (threadIdx.x >> 6);
    int lane = threadIdx.x & 63;
    if (node >= NN) return;
    int s = rowptr[node];
    int e = rowptr[node + 1];
    float2 acc = make_float2(0.f, 0.f);
    int j = s;
    for (; j + 8 <= e; j += 8) {
        int2 r[8];
#pragma unroll
        for (int k = 0; k < 8; ++k) r[k] = rec[j + k];
        float2 v[8];
#pragma unroll
        for (int k = 0; k < 8; ++k)
            v[k] = ((const float2*)(XW + (size_t)r[k].x * HD))[lane];
#pragma unroll
        for (int k = 0; k < 8; ++k) {
            float sc = __int_as_float(r[k].y);
            acc.x += v[k].x * sc;
            acc.y += v[k].y * sc;
        }
    }
    for (; j < e; ++j) {
        int2 r0 = rec[j];
        float2 v0 = ((const float2*)(XW + (size_t)r0.x * HD))[lane];
        float sc = __int_as_float(r0.y);
        acc.x += v0.x * sc;
        acc.y += v0.y * sc;
    }
    float d = dinv[node];
    float2 xi = ((const float2*)(XW + (size_t)node * HD))[lane];
    float2 bb = ((const float2*)bias)[lane];
    float2 h;
    h.x = d * (d * xi.x + acc.x) + bb.x;
    h.y = d * (d * xi.y + acc.y) + bb.y;
    h.x = h.x > 0.f ? h.x : expm1f(h.x);
    h.y = h.y > 0.f ? h.y : expm1f(h.y);
    ((float2*)(B + (size_t)node * HD))[lane] = h;
}

// ---------------- pool: one block per graph, no atomics ----------------
__global__ __launch_bounds__(256) void k_pool(const float* __restrict__ B,
                                              const float* __restrict__ Wout,
                                              const float* __restrict__ bout,
                                              const int* __restrict__ gptr,
                                              float* __restrict__ out) {
    __shared__ float wpart[4];
    const int g = blockIdx.x;
    const int lane = threadIdx.x & 63;
    const int wv = threadIdx.x >> 6;
    const int s = gptr[g];
    const int e = gptr[g + 1];

    float2 w = ((const float2*)Wout)[lane];
    float acc = 0.f;
    for (int node = s + wv; node < e; node += 4) {
        float2 h = ((const float2*)(B + (size_t)node * HD))[lane];
        acc += h.x * w.x + h.y * w.y;
    }
#pragma unroll
    for (int off = 32; off > 0; off >>= 1) acc += __shfl_down(acc, off);
    if (lane == 0) wpart[wv] = acc;
    __syncthreads();
    if (threadIdx.x == 0) {
        float total = wpart[0] + wpart[1] + wpart[2] + wpart[3];
        int cnt = e - s;
        out[g] = total / (float)(cnt > 0 ? cnt : 1) + bout[0];
    }
}

extern "C" void kernel_launch(void* const* d_in, const int* in_sizes, int n_in,
                              void* d_out, int out_size, void* d_ws, size_t ws_size,
                              hipStream_t stream) {
    const float* x    = (const float*)d_in[0];
    const float* W0   = (const float*)d_in[1];
    const float* b0   = (const float*)d_in[2];
    const float* W1   = (const float*)d_in[3];
    const float* b1   = (const float*)d_in[4];
    const float* W2   = (const float*)d_in[5];
    const float* b2   = (const float*)d_in[6];
    const float* Wout = (const float*)d_in[7];
    const float* bout = (const float*)d_in[8];
    const int*   erow = (const int*)d_in[9];
    const int*   ecol = erow + NE;
    const int*   batch = (const int*)d_in[10];
    float* out = (float*)d_out;

    float* A      = (float*)d_ws;                  // XW buffer [NN][HD]
    float* B      = A + (size_t)NN * HD;           // h buffer  [NN][HD]
    float* dinv   = B + (size_t)NN * HD;           // [NN]
    int*   cnt    = (int*)(dinv + NN);             // [NN] (reused as cursor)
    int*   rowptr = cnt + NN;                      // [NN+1]
    int*   gptr   = rowptr + NN + 1;               // [NG+1]
    int2*  rec    = (int2*)(gptr + NG + 1);        // [NE]

    hipMemsetAsync(cnt, 0, NN * sizeof(int), stream);
    k_count<<<(NE + 255) / 256, 256, 0, stream>>>(ecol, cnt);
    k_dinv<<<(NN + 255) / 256, 256, 0, stream>>>(cnt, dinv);
    k_scan<<<1, 1024, 0, stream>>>(cnt, rowptr);
    k_cursor<<<(NN + 255) / 256, 256, 0, stream>>>(rowptr, cnt);
    k_fill<<<(NE + 255) / 256, 256, 0, stream>>>(erow, ecol, dinv, cnt, rec);
    k_gptr<<<(NG + 1 + 255) / 256, 256, 0, stream>>>(batch, gptr);

    const float* Hin = x;
    const float* Wl[3] = {W0, W1, W2};
    const float* bl[3] = {b0, b1, b2};
    for (int l = 0; l < 3; ++l) {
        k_gemm<<<(NN + 63) / 64, 256, 0, stream>>>(Hin, Wl[l], A);
        k_gather<<<(NN + 3) / 4, 256, 0, stream>>>(A, B, rec, rowptr, dinv, bl[l]);
        Hin = B;
    }
    k_pool<<<NG, 256, 0, stream>>>(B, Wout, bout, gptr, out);
}